// Round 6
// baseline (533.346 us; speedup 1.0000x reference)
//
#include <hip/hip_runtime.h>
#include <math.h>

typedef __bf16 bf16_t;
typedef __attribute__((ext_vector_type(8))) __bf16 bf16x8;
typedef __attribute__((ext_vector_type(4))) float f32x4;

#define DMODEL 1024
#define NROWS  16384   // B*T
#define SEQLEN 4096

static __device__ __forceinline__ float sigmoidf_(float v) { return 1.f / (1.f + __expf(-v)); }

#define GLOAD16(gsrc, ldst) __builtin_amdgcn_global_load_lds(                     \
    (const __attribute__((address_space(1))) void*)(gsrc),                        \
    (__attribute__((address_space(3))) void*)(ldst), 16, 0, 0)

// ---------------- fused LayerNorm: stats + apply + f32->bf16, one block per row ----------------
__global__ __launch_bounds__(256) void ln_fused_kernel(const float* __restrict__ x,
                                                       const float* __restrict__ g,
                                                       const float* __restrict__ b,
                                                       bf16_t* __restrict__ out) {
  int row = blockIdx.x;
  int tid = threadIdx.x;
  const float4* xr = (const float4*)(x + (size_t)row * DMODEL);
  float4 v = xr[tid];
  float s  = v.x + v.y + v.z + v.w;
  float s2 = v.x*v.x + v.y*v.y + v.z*v.z + v.w*v.w;
  #pragma unroll
  for (int off = 32; off > 0; off >>= 1) {
    s  += __shfl_down(s, off);
    s2 += __shfl_down(s2, off);
  }
  __shared__ float sh[4], sh2[4];
  int lane = tid & 63, wid = tid >> 6;
  if (lane == 0) { sh[wid] = s; sh2[wid] = s2; }
  __syncthreads();
  s  = sh[0] + sh[1] + sh[2] + sh[3];
  s2 = sh2[0] + sh2[1] + sh2[2] + sh2[3];
  float m = s * (1.f / DMODEL);
  float var = fmaxf(s2 * (1.f / DMODEL) - m * m, 0.f);
  float rs = rsqrtf(var + 1e-5f);
  float4 gv = *(const float4*)&g[tid * 4];
  float4 bv = *(const float4*)&b[tid * 4];
  union { bf16_t h[4]; float2 f2; } u;
  u.h[0] = (bf16_t)((v.x - m) * rs * gv.x + bv.x);
  u.h[1] = (bf16_t)((v.y - m) * rs * gv.y + bv.y);
  u.h[2] = (bf16_t)((v.z - m) * rs * gv.z + bv.z);
  u.h[3] = (bf16_t)((v.w - m) * rs * gv.w + bv.w);
  *(float2*)&out[(size_t)row * DMODEL + tid * 4] = u.f2;
}

// ---------------- plain f32 -> bf16 convert ----------------
__global__ __launch_bounds__(256) void f32_to_bf16_kernel(const float* __restrict__ in,
                                                          bf16_t* __restrict__ out, int n) {
  int idx = (blockIdx.x * 256 + threadIdx.x) * 4;
  if (idx >= n) return;
  float4 v = *(const float4*)&in[idx];
  union { bf16_t h[4]; float2 f2; } u;
  u.h[0] = (bf16_t)v.x; u.h[1] = (bf16_t)v.y; u.h[2] = (bf16_t)v.z; u.h[3] = (bf16_t)v.w;
  *(float2*)&out[idx] = u.f2;
}

// ================= 256x256 / BK=64 / 8-wave / 8-phase (2 K-tiles per iter) =================
// Inline-asm ds_read_b128 (invisible to compiler waitcnt pass) + static buffer indices.
// Counted vmcnt: ph3-end vmcnt(6), ph7-end vmcnt(8); prologue 2 tiles then vmcnt(8);
// epilogue pair with vmcnt(0) at its mid-boundary. 3-bit XOR swizzle (involution on
// gload source + ds_read addr). Per-wave 128x64 C, 16 MFMA per phase, setprio-wrapped.

#define DSR128(dst, ptr, IMM) \
  asm volatile("ds_read_b128 %0, %1 offset:%2" : "=v"(dst) : "v"(ptr), "n"(IMM))

#define LOADA(d_, mh_)                                                     \
  DSR128(afrag[0][0], pA0, (d_)*32768+(mh_)*16384+0*2048);                 \
  DSR128(afrag[0][1], pA1, (d_)*32768+(mh_)*16384+0*2048);                 \
  DSR128(afrag[1][0], pA0, (d_)*32768+(mh_)*16384+1*2048);                 \
  DSR128(afrag[1][1], pA1, (d_)*32768+(mh_)*16384+1*2048);                 \
  DSR128(afrag[2][0], pA0, (d_)*32768+(mh_)*16384+2*2048);                 \
  DSR128(afrag[2][1], pA1, (d_)*32768+(mh_)*16384+2*2048);                 \
  DSR128(afrag[3][0], pA0, (d_)*32768+(mh_)*16384+3*2048);                 \
  DSR128(afrag[3][1], pA1, (d_)*32768+(mh_)*16384+3*2048);

#define LOADB(d_, nn_)                                                     \
  DSR128(bfrag[nn_][0][0], pB0, (d_)*32768+(nn_)*16384+0*2048);            \
  DSR128(bfrag[nn_][0][1], pB1, (d_)*32768+(nn_)*16384+0*2048);            \
  DSR128(bfrag[nn_][1][0], pB0, (d_)*32768+(nn_)*16384+1*2048);            \
  DSR128(bfrag[nn_][1][1], pB1, (d_)*32768+(nn_)*16384+1*2048);

#define MFMAQ(mh, nn)                                                             \
  { _Pragma("unroll")                                                             \
    for (int m_ = 0; m_ < 4; ++m_) {                                              \
      _Pragma("unroll")                                                           \
      for (int n2_ = 0; n2_ < 2; ++n2_) {                                         \
        acc[(mh)*4+m_][(nn)*2+n2_] = __builtin_amdgcn_mfma_f32_16x16x32_bf16(     \
            afrag[m_][0], bfrag[nn][n2_][0], acc[(mh)*4+m_][(nn)*2+n2_], 0,0,0);  \
        acc[(mh)*4+m_][(nn)*2+n2_] = __builtin_amdgcn_mfma_f32_16x16x32_bf16(     \
            afrag[m_][1], bfrag[nn][n2_][1], acc[(mh)*4+m_][(nn)*2+n2_], 0,0,0);  \
      }                                                                           \
    } }

#define PH_PRE()  __builtin_amdgcn_s_barrier();                                   \
                  asm volatile("s_waitcnt lgkmcnt(0)");                           \
                  __builtin_amdgcn_sched_barrier(0);                              \
                  __builtin_amdgcn_s_setprio(1)
#define PH_POST() __builtin_amdgcn_s_setprio(0);                                  \
                  __builtin_amdgcn_s_barrier()

// EPI: 0 outf=acc; 1 outb=bf16(silu(acc+bias)); 2 outf=res+bias+acc; 3 outf+=acc;
//      4 outf = res[idx] + sigmoid(acc+bias[col]) * aux[idx]
template<int EPI>
__global__ __launch_bounds__(512, 2) void gemm256_kernel(
    const bf16_t* __restrict__ A, int lda,
    const bf16_t* __restrict__ B, int ldb, int K, int nx,
    const float* __restrict__ bias,
    const float* __restrict__ res,
    const float* __restrict__ aux,
    float* __restrict__ outf, bf16_t* __restrict__ outb, int ldout) {
  __shared__ __align__(1024) char ldsp[131072];
  const int nwg = gridDim.x;
  const int bid = blockIdx.x;
  const int lid = (bid & 7) * (nwg >> 3) + (bid >> 3);   // bijective XCD swizzle (nwg%8==0)
  const int n0 = (lid % nx) * 256;
  const int r0 = (lid / nx) * 256;

  const int tid = threadIdx.x;
  const int lane = tid & 63;
  const int w = tid >> 6;
  const int wr = w >> 2, wc = w & 3;
  const int fr = lane & 15;
  const int q16 = (lane >> 4) * 16;
  const int swz = (fr & 7) << 4;
  const int aRow = wr * 64 + fr;
  const int bRow = wc * 32 + fr;

  typedef __attribute__((address_space(3))) char lds_char;
  lds_char* lb = (lds_char*)ldsp;
  lds_char* pA0 = lb + aRow * 128 + (q16 ^ swz);
  lds_char* pA1 = lb + aRow * 128 + ((64 + q16) ^ swz);
  lds_char* pB0 = lb + 65536 + bRow * 128 + (q16 ^ swz);
  lds_char* pB1 = lb + 65536 + bRow * 128 + ((64 + q16) ^ swz);

  const size_t lda_b = (size_t)lda * 2;
  const size_t ldb_b = (size_t)ldb * 2;
  const char* Ab = (const char*)A;
  const char* Bb = (const char*)B;
  const int trow = tid >> 3;
  const int scolb = (((tid & 7) ^ (trow & 7)) << 4);

  auto stageA = [&](int d, int h, int kt) {
    const char* src = Ab + (size_t)(r0 + h * 64 + trow) * lda_b + kt * 128 + scolb;
    char* dst = ldsp + d * 32768 + h * 16384 + tid * 16;
    GLOAD16(src, dst);
    GLOAD16(src + 128 * lda_b, dst + 8192);
  };
  auto stageB = [&](int d, int g, int kt) {
    const int r1 = 64 + trow;
    const char* s0 = Bb + (size_t)(n0 + (trow >> 5) * 64 + g * 32 + (trow & 31)) * ldb_b + kt * 128 + scolb;
    const char* s1 = Bb + (size_t)(n0 + (r1 >> 5) * 64 + g * 32 + (r1 & 31)) * ldb_b + kt * 128 + scolb;
    char* dst = ldsp + 65536 + d * 32768 + g * 16384 + tid * 16;
    GLOAD16(s0, dst);
    GLOAD16(s1, dst + 8192);
  };

  f32x4 acc[8][4];
  #pragma unroll
  for (int m = 0; m < 8; ++m)
    #pragma unroll
    for (int n = 0; n < 4; ++n) acc[m][n] = (f32x4){0.f, 0.f, 0.f, 0.f};
  bf16x8 afrag[4][2];
  bf16x8 bfrag[2][2][2];

  const int nt = K >> 6;       // even
  const int np = nt >> 1;

  // prologue: stage tile0 -> buf0, tile1 -> buf1 (16 loads), retire tile0
  stageA(0, 0, 0); stageB(0, 0, 0); stageB(0, 1, 0); stageA(0, 1, 0);
  stageA(1, 0, 1); stageB(1, 0, 1); stageB(1, 1, 1); stageA(1, 1, 1);
  asm volatile("s_waitcnt vmcnt(8)");
  __builtin_amdgcn_s_barrier();

  for (int i = 0; i < np - 1; ++i) {
    const int t2 = 2 * i + 2, t3 = 2 * i + 3;
    // ph0: even tile Q(0,0)
    LOADA(0, 0) LOADB(0, 0)
    PH_PRE(); MFMAQ(0, 0) PH_POST();
    // ph1: Q(0,1); stage A0(t2)
    stageA(0, 0, t2);
    LOADB(0, 1)
    PH_PRE(); MFMAQ(0, 1) PH_POST();
    // ph2: Q(1,0); stage B0(t2)
    stageB(0, 0, t2);
    LOADA(0, 1)
    PH_PRE(); MFMAQ(1, 0) PH_POST();
    // ph3: Q(1,1); stage B1(t2); boundary vmcnt(6) retires tile t3-1 (odd buf1 tile)
    stageB(0, 1, t2);
    PH_PRE(); MFMAQ(1, 1)
    __builtin_amdgcn_s_setprio(0);
    asm volatile("s_waitcnt vmcnt(6)");
    __builtin_amdgcn_s_barrier();
    // ph4: odd tile Q(0,0); stage A1(t2)
    stageA(0, 1, t2);
    LOADA(1, 0) LOADB(1, 0)
    PH_PRE(); MFMAQ(0, 0) PH_POST();
    // ph5: Q(0,1); stage A0(t3)
    stageA(1, 0, t3);
    LOADB(1, 1)
    PH_PRE(); MFMAQ(0, 1) PH_POST();
    // ph6: Q(1,0); stage B0(t3)
    stageB(1, 0, t3);
    LOADA(1, 1)
    PH_PRE(); MFMAQ(1, 0) PH_POST();
    // ph7: Q(1,1); stage B1(t3)+A1(t3); boundary vmcnt(8) retires tile t2
    stageB(1, 1, t3); stageA(1, 1, t3);
    PH_PRE(); MFMAQ(1, 1)
    __builtin_amdgcn_s_setprio(0);
    asm volatile("s_waitcnt vmcnt(8)");
    __builtin_amdgcn_s_barrier();
  }

  // epilogue pair (tiles nt-2 in buf0, nt-1 in buf1), no staging
  LOADA(0, 0) LOADB(0, 0)
  PH_PRE(); MFMAQ(0, 0) PH_POST();
  LOADB(0, 1)
  PH_PRE(); MFMAQ(0, 1) PH_POST();
  LOADA(0, 1)
  PH_PRE(); MFMAQ(1, 0) PH_POST();
  PH_PRE(); MFMAQ(1, 1)
  __builtin_amdgcn_s_setprio(0);
  asm volatile("s_waitcnt vmcnt(0)");
  __builtin_amdgcn_s_barrier();
  LOADA(1, 0) LOADB(1, 0)
  PH_PRE(); MFMAQ(0, 0) PH_POST();
  LOADB(1, 1)
  PH_PRE(); MFMAQ(0, 1) PH_POST();
  LOADA(1, 1)
  PH_PRE(); MFMAQ(1, 0) PH_POST();
  PH_PRE(); MFMAQ(1, 1)
  __builtin_amdgcn_s_setprio(0);

  const int rbase = (lane >> 4) * 4;
  #pragma unroll
  for (int mf = 0; mf < 8; ++mf) {
    #pragma unroll
    for (int n = 0; n < 4; ++n) {
      int row = r0 + wr * 128 + mf * 16 + rbase;
      int col = n0 + wc * 64 + n * 16 + fr;
      f32x4 v = acc[mf][n];
      #pragma unroll
      for (int j = 0; j < 4; ++j) {
        int r = row + j;
        float val = v[j];
        if (EPI == 0) {
          outf[(size_t)r * ldout + col] = val;
        } else if (EPI == 1) {
          float t2 = val + bias[col];
          t2 = t2 * sigmoidf_(t2);
          outb[(size_t)r * ldout + col] = (bf16_t)t2;
        } else if (EPI == 2) {
          outf[(size_t)r * ldout + col] = res[(size_t)r * 1024 + col] + bias[col] + val;
        } else if (EPI == 3) {
          outf[(size_t)r * ldout + col] += val;
        } else {
          size_t idx = (size_t)r * 1024 + col;
          outf[idx] = res[idx] + sigmoidf_(val + bias[col]) * aux[idx];
        }
      }
    }
  }
}

// ---------------- legacy 128x128 engine (beta/delta GEMM only) ----------------
template<int EPI>
__global__ __launch_bounds__(256) void gemm_bf16_kernel(
    const bf16_t* __restrict__ A, int lda,
    const bf16_t* __restrict__ B, int ldb, int K, int nx,
    float* __restrict__ outf, int ldout) {
  __shared__ __align__(16) bf16_t As[128 * 32];
  __shared__ __align__(16) bf16_t Bs[128 * 32];
  const int nwg = gridDim.x;
  const int bid = blockIdx.x;
  const int lid = (bid & 7) * (nwg >> 3) + (bid >> 3);
  const int n0 = (lid % nx) * 128;
  const int r0 = (lid / nx) * 128;

  const int tid = threadIdx.x;
  const int lane = tid & 63;
  const int w = tid >> 6;
  const int wr = w >> 1, wc = w & 1;
  const int srow0 = tid >> 2;
  const int srow1 = 64 + (tid >> 2);
  const int skk = (tid & 3) * 8;
  const int fr = lane & 15;
  const int ko = (lane >> 4) * 8;

  f32x4 acc[4][4];
  #pragma unroll
  for (int m = 0; m < 4; ++m)
    #pragma unroll
    for (int n = 0; n < 4; ++n) acc[m][n] = (f32x4){0.f, 0.f, 0.f, 0.f};

  for (int k0 = 0; k0 < K; k0 += 32) {
    GLOAD16(A + (size_t)(r0 + srow0) * lda + k0 + skk, (char*)As + w * 1024);
    GLOAD16(A + (size_t)(r0 + srow1) * lda + k0 + skk, (char*)As + 4096 + w * 1024);
    GLOAD16(B + (size_t)(n0 + srow0) * ldb + k0 + skk, (char*)Bs + w * 1024);
    GLOAD16(B + (size_t)(n0 + srow1) * ldb + k0 + skk, (char*)Bs + 4096 + w * 1024);
    __syncthreads();
    bf16x8 af[4], bfr[4];
    #pragma unroll
    for (int m = 0; m < 4; ++m)
      af[m] = *(const bf16x8*)&As[(wr * 64 + m * 16 + fr) * 32 + ko];
    #pragma unroll
    for (int n = 0; n < 4; ++n)
      bfr[n] = *(const bf16x8*)&Bs[(wc * 64 + n * 16 + fr) * 32 + ko];
    #pragma unroll
    for (int m = 0; m < 4; ++m)
      #pragma unroll
      for (int n = 0; n < 4; ++n)
        acc[m][n] = __builtin_amdgcn_mfma_f32_16x16x32_bf16(af[m], bfr[n], acc[m][n], 0, 0, 0);
    __syncthreads();
  }

  const int rbase = (lane >> 4) * 4;
  #pragma unroll
  for (int m = 0; m < 4; ++m) {
    #pragma unroll
    for (int n = 0; n < 4; ++n) {
      int row = r0 + wr * 64 + m * 16 + rbase;
      int col = n0 + wc * 64 + n * 16 + fr;
      f32x4 v = acc[m][n];
      #pragma unroll
      for (int j = 0; j < 4; ++j)
        outf[(size_t)(row + j) * ldout + col] = v[j];
    }
  }
}

// ---------------- elementwise: bd[16384,256] -> a,b arrays in [B,K,T] layout ----------------
__global__ __launch_bounds__(256) void ew_ab_kernel(
    const float* __restrict__ bd, const float* __restrict__ b_sel,
    const float* __restrict__ log_decay, const float* __restrict__ frequency,
    float* __restrict__ a_r, float* __restrict__ a_i,
    float* __restrict__ b_r, float* __restrict__ b_i) {
  __shared__ float T[32][257];
  int bb = blockIdx.x >> 7;            // 0..3
  int t0 = (blockIdx.x & 127) << 5;    // chunk of 32 timesteps
  int tid = threadIdx.x;
  #pragma unroll
  for (int p = 0; p < 32; ++p) {
    int idx = tid + p * 256;
    int tt = idx >> 8, j = idx & 255;
    T[tt][j] = bd[((size_t)bb * 4096 + t0 + tt) * 256 + j];
  }
  __syncthreads();
  #pragma unroll
  for (int p = 0; p < 8; ++p) {
    int idx = tid + p * 256;
    int tt = idx & 31, k = idx >> 5;
    float br_ = T[tt][k];
    float bi_ = T[tt][64 + k];
    float dd = T[tt][128 + k] + b_sel[k];
    float df = T[tt][192 + k] + b_sel[64 + k];
    float mag = sigmoidf_(log_decay[k] + 0.1f * tanhf(dd));
    float fr = frequency[k] + 0.05f * tanhf(df);
    float ar_ = mag * cosf(fr), ai_ = mag * sinf(fr);
    size_t o = ((size_t)bb * 64 + k) * 4096 + t0 + tt;
    a_r[o] = ar_; a_i[o] = ai_; b_r[o] = br_; b_i[o] = bi_;
  }
}

// ---------------- associative scan over T per (b,k); c in-place over b ----------------
__global__ __launch_bounds__(256) void scan_kernel(
    const float* __restrict__ a_r, const float* __restrict__ a_i,
    const float* b_r, const float* b_i,
    float* c_r, float* c_i) {
  int seq = blockIdx.x;
  size_t base = (size_t)seq * SEQLEN;
  int tid = threadIdx.x;
  int t0 = tid * 16;
  float Ar = 1.f, Ai = 0.f, Br = 0.f, Bi = 0.f;
  #pragma unroll
  for (int s = 0; s < 16; ++s) {
    size_t t = base + t0 + s;
    float ar = a_r[t], ai = a_i[t], br = b_r[t], bi = b_i[t];
    float nBr = ar * Br - ai * Bi + br;
    float nBi = ar * Bi + ai * Br + bi;
    Br = nBr; Bi = nBi;
    float nAr = ar * Ar - ai * Ai;
    float nAi = ar * Ai + ai * Ar;
    Ar = nAr; Ai = nAi;
  }
  __shared__ float sAr[256], sAi[256], sBr[256], sBi[256];
  sAr[tid] = Ar; sAi[tid] = Ai; sBr[tid] = Br; sBi[tid] = Bi;
  for (int off = 1; off < 256; off <<= 1) {
    __syncthreads();
    float pAr = 0.f, pAi = 0.f, pBr = 0.f, pBi = 0.f;
    if (tid >= off) { pAr = sAr[tid - off]; pAi = sAi[tid - off]; pBr = sBr[tid - off]; pBi = sBi[tid - off]; }
    __syncthreads();
    if (tid >= off) {
      float cAr = sAr[tid], cAi = sAi[tid], cBr = sBr[tid], cBi = sBi[tid];
      float nBr = cAr * pBr - cAi * pBi + cBr;
      float nBi = cAr * pBi + cAi * pBr + cBi;
      float nAr = cAr * pAr - cAi * pAi;
      float nAi = cAr * pAi + cAi * pAr;
      sAr[tid] = nAr; sAi[tid] = nAi; sBr[tid] = nBr; sBi[tid] = nBi;
    }
  }
  __syncthreads();
  float cr = (tid > 0) ? sBr[tid - 1] : 0.f;
  float ci = (tid > 0) ? sBi[tid - 1] : 0.f;
  #pragma unroll
  for (int s = 0; s < 16; ++s) {
    size_t t = base + t0 + s;
    float ar = a_r[t], ai = a_i[t], br = b_r[t], bi = b_i[t];
    float nr = ar * cr - ai * ci + br;
    float ni = ar * ci + ai * cr + bi;
    cr = nr; ci = ni;
    c_r[t] = cr; c_i[t] = ci;
  }
}

// ---------------- transpose c[B,K,T] -> cc[B*T, 128] bf16 ----------------
__global__ __launch_bounds__(256) void transpose_cc_kernel(
    const float* __restrict__ c_r, const float* __restrict__ c_i,
    bf16_t* __restrict__ cc) {
  __shared__ float Tr[64][65];
  __shared__ float Ti[64][65];
  int t0 = blockIdx.x * 64;
  int bb = blockIdx.y;
  int tid = threadIdx.x;
  int tt = tid & 63;
  int q = tid >> 6;
  #pragma unroll
  for (int p = 0; p < 16; ++p) {
    int k = p * 4 + q;
    size_t src = ((size_t)bb * 64 + k) * 4096 + t0 + tt;
    Tr[tt][k] = c_r[src];
    Ti[tt][k] = c_i[src];
  }
  __syncthreads();
  #pragma unroll
  for (int p = 0; p < 16; ++p) {
    int tt2 = p * 4 + q;
    int k = tid & 63;
    size_t row = (size_t)bb * 4096 + t0 + tt2;
    cc[row * 128 + k] = (bf16_t)Tr[tt2][k];
    cc[row * 128 + 64 + k] = (bf16_t)Ti[tt2][k];
  }
}

// ---------------- fold R into W_out: Weff[d][col] (bf16 out) ----------------
__global__ __launch_bounds__(256) void weff_kernel(const float* __restrict__ W_out,
                                                   const float* __restrict__ R,
                                                   bf16_t* __restrict__ Weff) {
  int idx = blockIdx.x * 256 + threadIdx.x;   // < 1024*128
  int d = idx >> 7, col = idx & 127;
  int k = col & 63, h = k >> 4, kk = k & 15;
  int off = (col < 64) ? 0 : 64;
  float s = 0.f;
  #pragma unroll
  for (int j = 0; j < 16; ++j)
    s += W_out[d * 128 + off + h * 16 + j] * R[h * 256 + j * 16 + kk];
  Weff[idx] = (bf16_t)s;
}

extern "C" void kernel_launch(void* const* d_in, const int* in_sizes, int n_in,
                              void* d_out, int out_size, void* d_ws, size_t ws_size,
                              hipStream_t stream) {
  (void)in_sizes; (void)n_in; (void)out_size; (void)ws_size;
  const float* x         = (const float*)d_in[0];
  const float* W_in      = (const float*)d_in[1];
  const float* log_decay = (const float*)d_in[2];
  const float* frequency = (const float*)d_in[3];
  const float* W_sel     = (const float*)d_in[4];
  const float* b_sel     = (const float*)d_in[5];
  const float* R         = (const float*)d_in[6];
  const float* W_out     = (const float*)d_in[7];
  const float* W_g       = (const float*)d_in[8];
  const float* b_g       = (const float*)d_in[9];
  const float* g1        = (const float*)d_in[10];
  const float* be1       = (const float*)d_in[11];
  const float* g2        = (const float*)d_in[12];
  const float* be2       = (const float*)d_in[13];
  const float* W1        = (const float*)d_in[14];
  const float* b1        = (const float*)d_in[15];
  const float* W2        = (const float*)d_in[16];
  const float* b2        = (const float*)d_in[17];
  float* out = (float*)d_out;
  float* ws  = (float*)d_ws;

  const size_t M1 = (size_t)1 << 20;
  float* bd   = ws;                        // 16384 x 256 f32 (dead before xmid)
  float* xmid = ws;                        // 16384 x 1024 f32
  float* a_r  = ws + 16 * M1;
  float* a_i  = ws + 20 * M1;
  float* b_rr = ws + 24 * M1;
  float* b_ii = ws + 28 * M1;
  float* hbuf = ws + 16 * M1;
  bf16_t* mid = (bf16_t*)(ws + 16 * M1);   // 16384 x 2048 bf16 per half
  bf16_t* xn  = (bf16_t*)(ws + 32 * M1);
  bf16_t* cc  = (bf16_t*)(ws + 40 * M1);
  bf16_t* Wbd = (bf16_t*)(ws + 41 * M1);                  // 256 x 1024
  bf16_t* Wgb = (bf16_t*)(ws + 41 * M1 + (128 << 10));    // 1024 x 1024
  bf16_t* W1b = (bf16_t*)(ws + 41 * M1 + (640 << 10));    // 4096 x 1024
  bf16_t* W2b = (bf16_t*)(ws + 43 * M1 + (640 << 10));    // 1024 x 4096
  bf16_t* Wef = (bf16_t*)(ws + 45 * M1 + (640 << 10));    // 1024 x 128

  dim3 blk(256);
  dim3 blk512(512);

  // LN1 fused -> xn bf16
  ln_fused_kernel<<<NROWS, blk, 0, stream>>>(x, g1, be1, xn);

  // weight conversions
  f32_to_bf16_kernel<<<128, blk, 0, stream>>>(W_in, Wbd, 128 * 1024);
  f32_to_bf16_kernel<<<128, blk, 0, stream>>>(W_sel, Wbd + 128 * 1024, 128 * 1024);
  f32_to_bf16_kernel<<<1024, blk, 0, stream>>>(W_g, Wgb, 1024 * 1024);
  f32_to_bf16_kernel<<<4096, blk, 0, stream>>>(W1, W1b, 4 * 1024 * 1024);
  f32_to_bf16_kernel<<<4096, blk, 0, stream>>>(W2, W2b, 4 * 1024 * 1024);
  weff_kernel<<<512, blk, 0, stream>>>(W_out, R, Wef);

  // beta/delta GEMM -> bd [16384,256] f32  (legacy engine; grid 256, nx=2)
  gemm_bf16_kernel<0><<<256, blk, 0, stream>>>(xn, 1024, Wbd, 1024, 1024, 2, bd, 256);

  // elementwise a,b in [B,K,T]
  ew_ab_kernel<<<512, blk, 0, stream>>>(bd, b_sel, log_decay, frequency, a_r, a_i, b_rr, b_ii);
  // scan (c in-place over b)
  scan_kernel<<<256, blk, 0, stream>>>(a_r, a_i, b_rr, b_ii, b_rr, b_ii);
  // transpose to [B*T,128] bf16
  transpose_cc_kernel<<<dim3(64, 4), blk, 0, stream>>>(b_rr, b_ii, cc);

  // h-projection: hbuf = cc @ Weff^T   (M=16384,N=1024,K=128; grid 256, nx=4)
  gemm256_kernel<0><<<256, blk512, 0, stream>>>(
      cc, 128, Wef, 128, 128, 4, nullptr, nullptr, nullptr, hbuf, nullptr, 1024);

  // gate GEMM + fuse: xmid = x + sigmoid(xn@Wg^T + b_g) * hbuf   (grid 256, nx=4)
  gemm256_kernel<4><<<256, blk512, 0, stream>>>(
      xn, 1024, Wgb, 1024, 1024, 4, b_g, x, hbuf, xmid, nullptr, 1024);

  // LN2 fused -> xn bf16 (reuse)
  ln_fused_kernel<<<NROWS, blk, 0, stream>>>(xmid, g2, be2, xn);

  // MLP: chunk over hidden dim (2 x 2048), full-M GEMMs, 2-pass W2 accumulation
  for (int h = 0; h < 2; ++h) {
    // W1 slice: mid = silu(xn @ W1[h]^T + b1[h])  (M=16384,N=2048,K=1024; grid 512, nx=8)
    gemm256_kernel<1><<<512, blk512, 0, stream>>>(
        xn, 1024, W1b + (size_t)h * 2048 * 1024, 1024, 1024, 8,
        b1 + h * 2048, nullptr, nullptr, nullptr, mid, 2048);
    // W2 partial: out (+)= mid @ W2[:,h]^T  (M=16384,N=1024,K=2048; grid 256, nx=4)
    if (h == 0) {
      gemm256_kernel<2><<<256, blk512, 0, stream>>>(
          mid, 2048, W2b, 4096, 2048, 4,
          b2, xmid, nullptr, out, nullptr, 1024);
    } else {
      gemm256_kernel<3><<<256, blk512, 0, stream>>>(
          mid, 2048, W2b + 2048, 4096, 2048, 4,
          nullptr, nullptr, nullptr, out, nullptr, 1024);
    }
  }
}

// Round 7
// 476.729 us; speedup vs baseline: 1.1188x; 1.1188x over previous
//
#include <hip/hip_runtime.h>
#include <math.h>

typedef __bf16 bf16_t;
typedef __attribute__((ext_vector_type(8))) __bf16 bf16x8;
typedef __attribute__((ext_vector_type(4))) float f32x4;

#define DMODEL 1024
#define NROWS  16384   // B*T
#define SEQLEN 4096

static __device__ __forceinline__ float sigmoidf_(float v) { return 1.f / (1.f + __expf(-v)); }

#define GLOAD16(gsrc, ldst) __builtin_amdgcn_global_load_lds(                     \
    (const __attribute__((address_space(1))) void*)(gsrc),                        \
    (__attribute__((address_space(3))) void*)(ldst), 16, 0, 0)

// ---------------- fused LayerNorm: stats + apply + f32->bf16, one block per row ----------------
__global__ __launch_bounds__(256) void ln_fused_kernel(const float* __restrict__ x,
                                                       const float* __restrict__ g,
                                                       const float* __restrict__ b,
                                                       bf16_t* __restrict__ out) {
  int row = blockIdx.x;
  int tid = threadIdx.x;
  const float4* xr = (const float4*)(x + (size_t)row * DMODEL);
  float4 v = xr[tid];
  float s  = v.x + v.y + v.z + v.w;
  float s2 = v.x*v.x + v.y*v.y + v.z*v.z + v.w*v.w;
  #pragma unroll
  for (int off = 32; off > 0; off >>= 1) {
    s  += __shfl_down(s, off);
    s2 += __shfl_down(s2, off);
  }
  __shared__ float sh[4], sh2[4];
  int lane = tid & 63, wid = tid >> 6;
  if (lane == 0) { sh[wid] = s; sh2[wid] = s2; }
  __syncthreads();
  s  = sh[0] + sh[1] + sh[2] + sh[3];
  s2 = sh2[0] + sh2[1] + sh2[2] + sh2[3];
  float m = s * (1.f / DMODEL);
  float var = fmaxf(s2 * (1.f / DMODEL) - m * m, 0.f);
  float rs = rsqrtf(var + 1e-5f);
  float4 gv = *(const float4*)&g[tid * 4];
  float4 bv = *(const float4*)&b[tid * 4];
  union { bf16_t h[4]; float2 f2; } u;
  u.h[0] = (bf16_t)((v.x - m) * rs * gv.x + bv.x);
  u.h[1] = (bf16_t)((v.y - m) * rs * gv.y + bv.y);
  u.h[2] = (bf16_t)((v.z - m) * rs * gv.z + bv.z);
  u.h[3] = (bf16_t)((v.w - m) * rs * gv.w + bv.w);
  *(float2*)&out[(size_t)row * DMODEL + tid * 4] = u.f2;
}

// ---------------- plain f32 -> bf16 convert ----------------
__global__ __launch_bounds__(256) void f32_to_bf16_kernel(const float* __restrict__ in,
                                                          bf16_t* __restrict__ out, int n) {
  int idx = (blockIdx.x * 256 + threadIdx.x) * 4;
  if (idx >= n) return;
  float4 v = *(const float4*)&in[idx];
  union { bf16_t h[4]; float2 f2; } u;
  u.h[0] = (bf16_t)v.x; u.h[1] = (bf16_t)v.y; u.h[2] = (bf16_t)v.z; u.h[3] = (bf16_t)v.w;
  *(float2*)&out[idx] = u.f2;
}

// ================= Engine B: 128x256 tile / BK=64 / 8 waves / single-buffer / 2 blocks/CU =======
// C[M,N] = A[M,K]*B[N,K]^T. 512 thr, waves 2(M)x4(N), wave tile 64x64 -> acc 64 VGPR.
// LDS 48KB: A[128x64] + B[256x64], one buffer; 2 barriers/K-tile; compiler-scheduled compute.
// Cross-block overlap (2 blocks/CU) hides the stage drain (m114 mechanism).
// 3-bit XOR swizzle on gload source col + ds_read col (involution) -> conflict-free.
// EPI: 0 outf=acc; 1 outb=bf16(silu(acc+bias)); 2 outf=res+bias+acc; 3 outf+=acc;
//      4 outf = res[idx] + sigmoid(acc+bias[col]) * (float)auxb[idx];  5 outb=bf16(acc)
template<int EPI>
__global__ __launch_bounds__(512, 4) void gemmB_kernel(
    const bf16_t* __restrict__ A, int lda,
    const bf16_t* __restrict__ B, int ldb, int K, int nx,
    const float* __restrict__ bias,
    const float* __restrict__ res,
    const bf16_t* __restrict__ auxb,
    float* __restrict__ outf, bf16_t* __restrict__ outb, int ldout) {
  __shared__ __align__(128) bf16_t Asm[128 * 64];   // 16 KB
  __shared__ __align__(128) bf16_t Bsm[256 * 64];   // 32 KB
  const int nwg = gridDim.x;
  const int bid = blockIdx.x;
  const int lid = (bid & 7) * (nwg >> 3) + (bid >> 3);   // bijective XCD swizzle (nwg%8==0)
  const int n0 = (lid % nx) * 256;
  const int r0 = (lid / nx) * 128;

  const int tid = threadIdx.x;
  const int lane = tid & 63;
  const int w = tid >> 6;
  const int wr = w >> 2, wc = w & 3;        // 2 x 4 wave grid
  const int fr = lane & 15;
  const int q16 = (lane >> 4) * 16;         // k-byte base within 64-bf16 row half
  const int swz = (fr & 7) << 4;
  const int trow = tid >> 3;                // staging row 0..63
  const int scolb = ((tid & 7) ^ (trow & 7)) << 4;

  const size_t lda_b = (size_t)lda * 2;
  const size_t ldb_b = (size_t)ldb * 2;
  const char* Ab = (const char*)A;
  const char* Bb = (const char*)B;
  char* lA = (char*)Asm;
  char* lB = (char*)Bsm;

  f32x4 acc[4][4];
  #pragma unroll
  for (int m = 0; m < 4; ++m)
    #pragma unroll
    for (int n = 0; n < 4; ++n) acc[m][n] = (f32x4){0.f, 0.f, 0.f, 0.f};

  for (int kt = 0; kt < K; kt += 64) {
    // stage: A 2 loads (rows trow, trow+64), B 4 loads (trow + 64*i)
    const char* sa = Ab + (size_t)(r0 + trow) * lda_b + kt * 2 + scolb;
    GLOAD16(sa, lA + tid * 16);
    GLOAD16(sa + 64 * lda_b, lA + 8192 + tid * 16);
    const char* sb = Bb + (size_t)(n0 + trow) * ldb_b + kt * 2 + scolb;
    GLOAD16(sb, lB + tid * 16);
    GLOAD16(sb + 64 * ldb_b,  lB + 8192  + tid * 16);
    GLOAD16(sb + 128 * ldb_b, lB + 16384 + tid * 16);
    GLOAD16(sb + 192 * ldb_b, lB + 24576 + tid * 16);
    __syncthreads();   // compiler inserts vmcnt(0) drain
    #pragma unroll
    for (int kh = 0; kh < 2; ++kh) {
      bf16x8 af[4], bv[4];
      #pragma unroll
      for (int m = 0; m < 4; ++m)
        af[m] = *(const bf16x8*)(lA + (wr * 64 + m * 16 + fr) * 128 + ((kh * 64 + q16) ^ swz));
      #pragma unroll
      for (int n = 0; n < 4; ++n)
        bv[n] = *(const bf16x8*)(lB + (wc * 64 + n * 16 + fr) * 128 + ((kh * 64 + q16) ^ swz));
      #pragma unroll
      for (int m = 0; m < 4; ++m)
        #pragma unroll
        for (int n = 0; n < 4; ++n)
          acc[m][n] = __builtin_amdgcn_mfma_f32_16x16x32_bf16(af[m], bv[n], acc[m][n], 0, 0, 0);
    }
    __syncthreads();   // protect buffer before next stage
  }

  const int rbase = (lane >> 4) * 4;
  #pragma unroll
  for (int mf = 0; mf < 4; ++mf) {
    #pragma unroll
    for (int n = 0; n < 4; ++n) {
      int row = r0 + wr * 64 + mf * 16 + rbase;
      int col = n0 + wc * 64 + n * 16 + fr;
      f32x4 v = acc[mf][n];
      #pragma unroll
      for (int j = 0; j < 4; ++j) {
        int r = row + j;
        float val = v[j];
        if (EPI == 0) {
          outf[(size_t)r * ldout + col] = val;
        } else if (EPI == 1) {
          float t2 = val + bias[col];
          t2 = t2 * sigmoidf_(t2);
          outb[(size_t)r * ldout + col] = (bf16_t)t2;
        } else if (EPI == 2) {
          outf[(size_t)r * ldout + col] = res[(size_t)r * 1024 + col] + bias[col] + val;
        } else if (EPI == 3) {
          outf[(size_t)r * ldout + col] += val;
        } else if (EPI == 4) {
          size_t idx = (size_t)r * 1024 + col;
          outf[idx] = res[idx] + sigmoidf_(val + bias[col]) * (float)auxb[idx];
        } else {
          outb[(size_t)r * ldout + col] = (bf16_t)val;
        }
      }
    }
  }
}

// ---------------- legacy 128x128 engine (beta/delta GEMM only) ----------------
template<int EPI>
__global__ __launch_bounds__(256) void gemm_bf16_kernel(
    const bf16_t* __restrict__ A, int lda,
    const bf16_t* __restrict__ B, int ldb, int K, int nx,
    float* __restrict__ outf, int ldout) {
  __shared__ __align__(16) bf16_t As[128 * 32];
  __shared__ __align__(16) bf16_t Bs[128 * 32];
  const int nwg = gridDim.x;
  const int bid = blockIdx.x;
  const int lid = (bid & 7) * (nwg >> 3) + (bid >> 3);
  const int n0 = (lid % nx) * 128;
  const int r0 = (lid / nx) * 128;

  const int tid = threadIdx.x;
  const int lane = tid & 63;
  const int w = tid >> 6;
  const int wr = w >> 1, wc = w & 1;
  const int srow0 = tid >> 2;
  const int srow1 = 64 + (tid >> 2);
  const int skk = (tid & 3) * 8;
  const int fr = lane & 15;
  const int ko = (lane >> 4) * 8;

  f32x4 acc[4][4];
  #pragma unroll
  for (int m = 0; m < 4; ++m)
    #pragma unroll
    for (int n = 0; n < 4; ++n) acc[m][n] = (f32x4){0.f, 0.f, 0.f, 0.f};

  for (int k0 = 0; k0 < K; k0 += 32) {
    GLOAD16(A + (size_t)(r0 + srow0) * lda + k0 + skk, (char*)As + w * 1024);
    GLOAD16(A + (size_t)(r0 + srow1) * lda + k0 + skk, (char*)As + 4096 + w * 1024);
    GLOAD16(B + (size_t)(n0 + srow0) * ldb + k0 + skk, (char*)Bs + w * 1024);
    GLOAD16(B + (size_t)(n0 + srow1) * ldb + k0 + skk, (char*)Bs + 4096 + w * 1024);
    __syncthreads();
    bf16x8 af[4], bfr[4];
    #pragma unroll
    for (int m = 0; m < 4; ++m)
      af[m] = *(const bf16x8*)&As[(wr * 64 + m * 16 + fr) * 32 + ko];
    #pragma unroll
    for (int n = 0; n < 4; ++n)
      bfr[n] = *(const bf16x8*)&Bs[(wc * 64 + n * 16 + fr) * 32 + ko];
    #pragma unroll
    for (int m = 0; m < 4; ++m)
      #pragma unroll
      for (int n = 0; n < 4; ++n)
        acc[m][n] = __builtin_amdgcn_mfma_f32_16x16x32_bf16(af[m], bfr[n], acc[m][n], 0, 0, 0);
    __syncthreads();
  }

  const int rbase = (lane >> 4) * 4;
  #pragma unroll
  for (int m = 0; m < 4; ++m) {
    #pragma unroll
    for (int n = 0; n < 4; ++n) {
      int row = r0 + wr * 64 + m * 16 + rbase;
      int col = n0 + wc * 64 + n * 16 + fr;
      f32x4 v = acc[m][n];
      #pragma unroll
      for (int j = 0; j < 4; ++j)
        outf[(size_t)(row + j) * ldout + col] = v[j];
    }
  }
}

// ---------------- elementwise: bd[16384,256] -> a,b arrays in [B,K,T] layout ----------------
__global__ __launch_bounds__(256) void ew_ab_kernel(
    const float* __restrict__ bd, const float* __restrict__ b_sel,
    const float* __restrict__ log_decay, const float* __restrict__ frequency,
    float* __restrict__ a_r, float* __restrict__ a_i,
    float* __restrict__ b_r, float* __restrict__ b_i) {
  __shared__ float T[32][257];
  int bb = blockIdx.x >> 7;            // 0..3
  int t0 = (blockIdx.x & 127) << 5;    // chunk of 32 timesteps
  int tid = threadIdx.x;
  #pragma unroll
  for (int p = 0; p < 32; ++p) {
    int idx = tid + p * 256;
    int tt = idx >> 8, j = idx & 255;
    T[tt][j] = bd[((size_t)bb * 4096 + t0 + tt) * 256 + j];
  }
  __syncthreads();
  #pragma unroll
  for (int p = 0; p < 8; ++p) {
    int idx = tid + p * 256;
    int tt = idx & 31, k = idx >> 5;
    float br_ = T[tt][k];
    float bi_ = T[tt][64 + k];
    float dd = T[tt][128 + k] + b_sel[k];
    float df = T[tt][192 + k] + b_sel[64 + k];
    float mag = sigmoidf_(log_decay[k] + 0.1f * tanhf(dd));
    float fr = frequency[k] + 0.05f * tanhf(df);
    float ar_ = mag * cosf(fr), ai_ = mag * sinf(fr);
    size_t o = ((size_t)bb * 64 + k) * 4096 + t0 + tt;
    a_r[o] = ar_; a_i[o] = ai_; b_r[o] = br_; b_i[o] = bi_;
  }
}

// ---------------- associative scan over T per (b,k); c in-place over b ----------------
__global__ __launch_bounds__(256) void scan_kernel(
    const float* __restrict__ a_r, const float* __restrict__ a_i,
    const float* b_r, const float* b_i,
    float* c_r, float* c_i) {
  int seq = blockIdx.x;
  size_t base = (size_t)seq * SEQLEN;
  int tid = threadIdx.x;
  int t0 = tid * 16;
  float Ar = 1.f, Ai = 0.f, Br = 0.f, Bi = 0.f;
  #pragma unroll
  for (int s = 0; s < 16; ++s) {
    size_t t = base + t0 + s;
    float ar = a_r[t], ai = a_i[t], br = b_r[t], bi = b_i[t];
    float nBr = ar * Br - ai * Bi + br;
    float nBi = ar * Bi + ai * Br + bi;
    Br = nBr; Bi = nBi;
    float nAr = ar * Ar - ai * Ai;
    float nAi = ar * Ai + ai * Ar;
    Ar = nAr; Ai = nAi;
  }
  __shared__ float sAr[256], sAi[256], sBr[256], sBi[256];
  sAr[tid] = Ar; sAi[tid] = Ai; sBr[tid] = Br; sBi[tid] = Bi;
  for (int off = 1; off < 256; off <<= 1) {
    __syncthreads();
    float pAr = 0.f, pAi = 0.f, pBr = 0.f, pBi = 0.f;
    if (tid >= off) { pAr = sAr[tid - off]; pAi = sAi[tid - off]; pBr = sBr[tid - off]; pBi = sBi[tid - off]; }
    __syncthreads();
    if (tid >= off) {
      float cAr = sAr[tid], cAi = sAi[tid], cBr = sBr[tid], cBi = sBi[tid];
      float nBr = cAr * pBr - cAi * pBi + cBr;
      float nBi = cAr * pBi + cAi * pBr + cBi;
      float nAr = cAr * pAr - cAi * pAi;
      float nAi = cAr * pAi + cAi * pAr;
      sAr[tid] = nAr; sAi[tid] = nAi; sBr[tid] = nBr; sBi[tid] = nBi;
    }
  }
  __syncthreads();
  float cr = (tid > 0) ? sBr[tid - 1] : 0.f;
  float ci = (tid > 0) ? sBi[tid - 1] : 0.f;
  #pragma unroll
  for (int s = 0; s < 16; ++s) {
    size_t t = base + t0 + s;
    float ar = a_r[t], ai = a_i[t], br = b_r[t], bi = b_i[t];
    float nr = ar * cr - ai * ci + br;
    float ni = ar * ci + ai * cr + bi;
    cr = nr; ci = ni;
    c_r[t] = cr; c_i[t] = ci;
  }
}

// ---------------- transpose c[B,K,T] -> cc[B*T, 128] bf16 ----------------
__global__ __launch_bounds__(256) void transpose_cc_kernel(
    const float* __restrict__ c_r, const float* __restrict__ c_i,
    bf16_t* __restrict__ cc) {
  __shared__ float Tr[64][65];
  __shared__ float Ti[64][65];
  int t0 = blockIdx.x * 64;
  int bb = blockIdx.y;
  int tid = threadIdx.x;
  int tt = tid & 63;
  int q = tid >> 6;
  #pragma unroll
  for (int p = 0; p < 16; ++p) {
    int k = p * 4 + q;
    size_t src = ((size_t)bb * 64 + k) * 4096 + t0 + tt;
    Tr[tt][k] = c_r[src];
    Ti[tt][k] = c_i[src];
  }
  __syncthreads();
  #pragma unroll
  for (int p = 0; p < 16; ++p) {
    int tt2 = p * 4 + q;
    int k = tid & 63;
    size_t row = (size_t)bb * 4096 + t0 + tt2;
    cc[row * 128 + k] = (bf16_t)Tr[tt2][k];
    cc[row * 128 + 64 + k] = (bf16_t)Ti[tt2][k];
  }
}

// ---------------- fold R into W_out: Weff[d][col] (bf16 out) ----------------
__global__ __launch_bounds__(256) void weff_kernel(const float* __restrict__ W_out,
                                                   const float* __restrict__ R,
                                                   bf16_t* __restrict__ Weff) {
  int idx = blockIdx.x * 256 + threadIdx.x;   // < 1024*128
  int d = idx >> 7, col = idx & 127;
  int k = col & 63, h = k >> 4, kk = k & 15;
  int off = (col < 64) ? 0 : 64;
  float s = 0.f;
  #pragma unroll
  for (int j = 0; j < 16; ++j)
    s += W_out[d * 128 + off + h * 16 + j] * R[h * 256 + j * 16 + kk];
  Weff[idx] = (bf16_t)s;
}

extern "C" void kernel_launch(void* const* d_in, const int* in_sizes, int n_in,
                              void* d_out, int out_size, void* d_ws, size_t ws_size,
                              hipStream_t stream) {
  (void)in_sizes; (void)n_in; (void)out_size;
  const float* x         = (const float*)d_in[0];
  const float* W_in      = (const float*)d_in[1];
  const float* log_decay = (const float*)d_in[2];
  const float* frequency = (const float*)d_in[3];
  const float* W_sel     = (const float*)d_in[4];
  const float* b_sel     = (const float*)d_in[5];
  const float* R         = (const float*)d_in[6];
  const float* W_out     = (const float*)d_in[7];
  const float* W_g       = (const float*)d_in[8];
  const float* b_g       = (const float*)d_in[9];
  const float* g1        = (const float*)d_in[10];
  const float* be1       = (const float*)d_in[11];
  const float* g2        = (const float*)d_in[12];
  const float* be2       = (const float*)d_in[13];
  const float* W1        = (const float*)d_in[14];
  const float* b1        = (const float*)d_in[15];
  const float* W2        = (const float*)d_in[16];
  const float* b2        = (const float*)d_in[17];
  float* out = (float*)d_out;
  float* ws  = (float*)d_ws;

  const size_t M1 = (size_t)1 << 20;
  // full path needs ~247 MB: mid full [16M,48M), xn @48M, cc @56M, weights @57M..
  const bool full = ws_size >= (size_t)62 * M1 * sizeof(float);   // 248 MB

  float* bd   = ws;                        // 16384 x 256 f32 (dead before xmid)
  float* xmid = ws;                        // 16384 x 1024 f32
  float* a_r  = ws + 16 * M1;
  float* a_i  = ws + 20 * M1;
  float* b_rr = ws + 24 * M1;
  float* b_ii = ws + 28 * M1;
  bf16_t* hbufb = (bf16_t*)(ws + 16 * M1); // 16384 x 1024 bf16 (dead before mid)
  bf16_t* mid = (bf16_t*)(ws + 16 * M1);   // full: 16384x4096; chunked: 16384x2048
  size_t wx = full ? 48 * M1 : 32 * M1;    // xn offset
  size_t wc_off = full ? 56 * M1 : 40 * M1;
  size_t wb = full ? 57 * M1 : 41 * M1;    // weights base
  bf16_t* xn  = (bf16_t*)(ws + wx);
  bf16_t* cc  = (bf16_t*)(ws + wc_off);
  bf16_t* Wbd = (bf16_t*)(ws + wb);                    // 256 x 1024
  bf16_t* Wgb = (bf16_t*)(ws + wb + (128 << 10));      // 1024 x 1024
  bf16_t* W1b = (bf16_t*)(ws + wb + (640 << 10));      // 4096 x 1024
  bf16_t* W2b = (bf16_t*)(ws + wb + 2 * M1 + (640 << 10)); // 1024 x 4096
  bf16_t* Wef = (bf16_t*)(ws + wb + 4 * M1 + (640 << 10)); // 1024 x 128

  dim3 blk(256);
  dim3 blk512(512);

  // LN1 fused -> xn bf16
  ln_fused_kernel<<<NROWS, blk, 0, stream>>>(x, g1, be1, xn);

  // weight conversions
  f32_to_bf16_kernel<<<128, blk, 0, stream>>>(W_in, Wbd, 128 * 1024);
  f32_to_bf16_kernel<<<128, blk, 0, stream>>>(W_sel, Wbd + 128 * 1024, 128 * 1024);
  f32_to_bf16_kernel<<<1024, blk, 0, stream>>>(W_g, Wgb, 1024 * 1024);
  f32_to_bf16_kernel<<<4096, blk, 0, stream>>>(W1, W1b, 4 * 1024 * 1024);
  f32_to_bf16_kernel<<<4096, blk, 0, stream>>>(W2, W2b, 4 * 1024 * 1024);
  weff_kernel<<<512, blk, 0, stream>>>(W_out, R, Wef);

  // beta/delta GEMM -> bd [16384,256] f32  (legacy engine; grid 256, nx=2)
  gemm_bf16_kernel<0><<<256, blk, 0, stream>>>(xn, 1024, Wbd, 1024, 1024, 2, bd, 256);

  // elementwise a,b in [B,K,T]
  ew_ab_kernel<<<512, blk, 0, stream>>>(bd, b_sel, log_decay, frequency, a_r, a_i, b_rr, b_ii);
  // scan (c in-place over b)
  scan_kernel<<<256, blk, 0, stream>>>(a_r, a_i, b_rr, b_ii, b_rr, b_ii);
  // transpose to [B*T,128] bf16
  transpose_cc_kernel<<<dim3(64, 4), blk, 0, stream>>>(b_rr, b_ii, cc);

  // h-projection: hbufb = bf16(cc @ Weff^T)   (M=16384,N=1024,K=128; grid 512, nx=4)
  gemmB_kernel<5><<<512, blk512, 0, stream>>>(
      cc, 128, Wef, 128, 128, 4, nullptr, nullptr, nullptr, nullptr, hbufb, 1024);

  // gate GEMM + fuse: xmid = x + sigmoid(xn@Wg^T + b_g) * hbufb   (grid 512, nx=4)
  gemmB_kernel<4><<<512, blk512, 0, stream>>>(
      xn, 1024, Wgb, 1024, 1024, 4, b_g, x, hbufb, xmid, nullptr, 1024);

  // LN2 fused -> xn bf16 (reuse)
  ln_fused_kernel<<<NROWS, blk, 0, stream>>>(xmid, g2, be2, xn);

  if (full) {
    // W1 full: mid = silu(xn @ W1^T + b1)  (M=16384,N=4096,K=1024; grid 2048, nx=16)
    gemmB_kernel<1><<<2048, blk512, 0, stream>>>(
        xn, 1024, W1b, 1024, 1024, 16, b1, nullptr, nullptr, nullptr, mid, 4096);
    // W2 full: out = xmid + b2 + mid @ W2^T  (M=16384,N=1024,K=4096; grid 512, nx=4)
    gemmB_kernel<2><<<512, blk512, 0, stream>>>(
        mid, 4096, W2b, 4096, 4096, 4, b2, xmid, nullptr, out, nullptr, 1024);
  } else {
    for (int h = 0; h < 2; ++h) {
      gemmB_kernel<1><<<1024, blk512, 0, stream>>>(
          xn, 1024, W1b + (size_t)h * 2048 * 1024, 1024, 1024, 8,
          b1 + h * 2048, nullptr, nullptr, nullptr, mid, 2048);
      if (h == 0) {
        gemmB_kernel<2><<<512, blk512, 0, stream>>>(
            mid, 2048, W2b, 4096, 2048, 4, b2, xmid, nullptr, out, nullptr, 1024);
      } else {
        gemmB_kernel<3><<<512, blk512, 0, stream>>>(
            mid, 2048, W2b + 2048, 4096, 2048, 4, nullptr, nullptr, nullptr, out, nullptr, 1024);
      }
    }
  }
}